// Round 11
// baseline (510.883 us; speedup 1.0000x reference)
//
#include <hip/hip_runtime.h>

// VQ codebook nearest-neighbor: xs [32768,512] f32, W [8192,512] f32
// out[i] = W[argmin_j ||xs_i - W_j||^2]
//
// R11: f16 MFMA approx pass. 128x128 tile, 4 waves (2x2), wave-tile 64x64
//      (acc 64 AGPR; total regs <= 128 -> 16 waves/CU = 4 blocks/CU, the
//      R3-proven high-occupancy regime where the loop runs at the MFMA
//      issue floor). Dbuf 2x16KB = 32KB LDS, R10-proven stage(t+1) loop.
//      + R10's lean in-register u32 best-2 epilogue + exact fp32 fixup.

#define M_TOK 32768
#define N_EMB 8192
#define D_K   512
#define WOFF  2048.0f
#define QMASK 0xFFFFFF80u     // 7 low bits = local col (128-wide tile); quant 0.03125
#define BAND  0.375f
#define NT    16              // K-tiles of 32

typedef _Float16 f16;
typedef __attribute__((ext_vector_type(8))) _Float16 f16x8;
typedef __attribute__((ext_vector_type(4))) _Float16 f16x4;
typedef __attribute__((ext_vector_type(4))) float f32x4;
typedef unsigned long long u64;
typedef unsigned int u32;

__device__ __forceinline__ void gload16(const void* g, void* l) {
  __builtin_amdgcn_global_load_lds(
      (const __attribute__((address_space(1))) unsigned int*)g,
      (__attribute__((address_space(3))) unsigned int*)l, 16, 0, 0);
}

__device__ __forceinline__ u32 map_f(float f) {   // exact order-preserving (fixup)
  u32 u = __float_as_uint(f);
  return u ^ ((u & 0x80000000u) ? 0xFFFFFFFFu : 0x80000000u);
}
__device__ __forceinline__ float qval(u32 key) {  // quantized approx value
  return __uint_as_float(key & QMASK) - WOFF;
}

// ---------------- fp32 -> f16 X (round-nearest) ----------------
__global__ __launch_bounds__(256) void convert_hi_kernel(const float* __restrict__ src,
                                                         f16* __restrict__ dst, int n4) {
  int e = blockIdx.x * 256 + threadIdx.x;
  if (e >= n4) return;
  float4 v = ((const float4*)src)[e];
  f16x4 h; h.x = (f16)v.x; h.y = (f16)v.y; h.z = (f16)v.z; h.w = (f16)v.w;
  *(f16x4*)(dst + (size_t)e * 4) = h;
}

// ---------------- W: convert + ||w||^2 fused ----------------
__global__ __launch_bounds__(256) void convw_norm_kernel(const float* __restrict__ w,
                                                         f16* __restrict__ Wh,
                                                         float* __restrict__ wnorm,
                                                         int* __restrict__ cnt) {
  if (blockIdx.x == 0 && threadIdx.x == 0) *cnt = 0;
  const int row  = blockIdx.x * 4 + (threadIdx.x >> 6);
  const int lane = threadIdx.x & 63;
  const float4* wr = (const float4*)(w + (size_t)row * D_K);
  float4 v0 = wr[lane * 2], v1 = wr[lane * 2 + 1];
  f16x8 h;
  h[0] = (f16)v0.x; h[1] = (f16)v0.y; h[2] = (f16)v0.z; h[3] = (f16)v0.w;
  h[4] = (f16)v1.x; h[5] = (f16)v1.y; h[6] = (f16)v1.z; h[7] = (f16)v1.w;
  *(f16x8*)(Wh + (size_t)row * D_K + lane * 8) = h;
  float s = v0.x*v0.x + v0.y*v0.y + v0.z*v0.z + v0.w*v0.w
          + v1.x*v1.x + v1.y*v1.y + v1.z*v1.z + v1.w*v1.w;
  #pragma unroll
  for (int off = 32; off; off >>= 1) s += __shfl_xor(s, off);
  if (lane == 0) wnorm[row] = s;
}

// ---------------- approx distance + per-block best-2 ----------------
// Dbuf safety (R10-proven): stage(t+1)->buf^1 whose reads were drained by the
// previous iter's __syncthreads (vmcnt0+lgkm0+barrier); stage issued after it.
__global__ __launch_bounds__(256, 4) void dist_mfma_kernel(
    const f16* __restrict__ Xh, const f16* __restrict__ Wh,
    const float* __restrict__ wnorm, uint2* __restrict__ partials) {
  __shared__ char smem[32768];   // buf b at b*16384: [A 8KB | B 8KB]

  int bid = (int)blockIdx.x;
  const int swz = (bid & 7) * 2048 + (bid >> 3);   // XCD swizzle (16384 % 8 == 0)
  const int rt = swz & 255, ct = swz >> 8;          // rt fast -> B-panel L2 reuse
  const int row0 = rt * 128, col0 = ct * 128;

  const int tid  = threadIdx.x;
  const int w    = tid >> 6, lane = tid & 63;
  const int wr   = w >> 1,  wc   = w & 1;           // 2x2 wave grid
  const int g    = lane >> 4, cl = lane & 15;

  const char* gA = (const char*)Xh + (size_t)row0 * 1024;   // row = 1024 B
  const char* gB = (const char*)Wh + (size_t)col0 * 1024;

  // stage source offsets (pre-swizzled, R2/R3-proven (r>>1)&3 pattern);
  // chunk c = q*256 + tid (16B), tile row r = c>>2; same layout for A and B.
  int srcoff[2];
  #pragma unroll
  for (int q = 0; q < 2; ++q) {
    const int c = q * 256 + tid;
    const int r = c >> 2;
    srcoff[q] = r * 1024 + (((c & 3) ^ ((r >> 1) & 3)) * 16);
  }

  // LDS frag-read offsets (row stride 64B, slot g ^ ((row>>1)&3))
  int offA[4], offB[4];
  #pragma unroll
  for (int m = 0; m < 4; ++m) {
    const int rl = wr * 64 + m * 16 + cl;
    offA[m] = rl * 64 + ((g ^ ((rl >> 1) & 3)) * 16);
  }
  #pragma unroll
  for (int n = 0; n < 4; ++n) {
    const int rl = wc * 64 + n * 16 + cl;
    offB[n] = 8192 + rl * 64 + ((g ^ ((rl >> 1) & 3)) * 16);
  }

  #define STG(bo, kt)                                                          \
    { _Pragma("unroll") for (int q = 0; q < 2; ++q)                            \
        gload16(gA + srcoff[q] + (kt) * 64,                                    \
                smem + (bo) + q * 4096 + w * 1024);                            \
      _Pragma("unroll") for (int q = 0; q < 2; ++q)                            \
        gload16(gB + srcoff[q] + (kt) * 64,                                    \
                smem + (bo) + 8192 + q * 4096 + w * 1024); }

  f32x4 acc[4][4];
  #pragma unroll
  for (int i = 0; i < 4; i++)
    #pragma unroll
    for (int j = 0; j < 4; j++) acc[i][j] = (f32x4)(0.0f);

  STG(0, 0);
  __syncthreads();

  for (int t = 0; t < NT; ++t) {
    const int rb = (t & 1) * 16384, sb = rb ^ 16384;
    if (t < NT - 1) STG(sb, t + 1);

    f16x8 a[4], b[4];
    #pragma unroll
    for (int m = 0; m < 4; ++m) a[m] = *(const f16x8*)(smem + rb + offA[m]);
    #pragma unroll
    for (int n = 0; n < 4; ++n) b[n] = *(const f16x8*)(smem + rb + offB[n]);

    #pragma unroll
    for (int m = 0; m < 4; ++m)
      #pragma unroll
      for (int n = 0; n < 4; ++n)
        acc[m][n] = __builtin_amdgcn_mfma_f32_16x16x32_f16(a[m], b[n], acc[m][n], 0, 0, 0);

    __syncthreads();   // drains vmcnt (stage landed) + lgkm (buf reads done)
  }
  #undef STG

  // ---- epilogue: u32 keys (quantized bits | 7-bit local col), best-2 ----
  float wnp[4];
  u32 colb[4];
  #pragma unroll
  for (int n = 0; n < 4; ++n) {
    const int colL = wc * 64 + n * 16 + cl;
    wnp[n]  = wnorm[col0 + colL] + WOFF;
    colb[n] = (u32)colL;
  }

  uint2* cmb = (uint2*)smem;   // [128 rows][2 wc] = 2KB (loop fully drained)

  #pragma unroll
  for (int m = 0; m < 4; ++m) {
    #pragma unroll
    for (int r = 0; r < 4; ++r) {
      float s0 = fmaf(-2.0f, acc[m][0][r], wnp[0]);
      float s1 = fmaf(-2.0f, acc[m][1][r], wnp[1]);
      float s2 = fmaf(-2.0f, acc[m][2][r], wnp[2]);
      float s3 = fmaf(-2.0f, acc[m][3][r], wnp[3]);
      u32 k0 = (__float_as_uint(s0) & QMASK) | colb[0];
      u32 k1 = (__float_as_uint(s1) & QMASK) | colb[1];
      u32 k2 = (__float_as_uint(s2) & QMASK) | colb[2];
      u32 k3 = (__float_as_uint(s3) & QMASK) | colb[3];
      u32 pa = min(k0, k1), pb = max(k0, k1);
      u32 pc = min(k2, k3), pd = max(k2, k3);
      u32 c1 = min(pa, pc);
      u32 c2 = min(max(pa, pc), min(pb, pd));
      #pragma unroll
      for (int off = 1; off < 16; off <<= 1) {
        u32 o1 = __shfl_xor(c1, off), o2 = __shfl_xor(c2, off);
        u32 n1 = min(c1, o1);
        c2 = min(min(c2, o2), max(c1, o1));
        c1 = n1;
      }
      if (cl == 0) cmb[(wr * 64 + m * 16 + g * 4 + r) * 2 + wc] = make_uint2(c1, c2);
    }
  }
  __syncthreads();
  if (tid < 128) {
    uint2 A = cmb[tid * 2], B = cmb[tid * 2 + 1];
    u32 c1 = min(A.x, B.x);
    u32 c2 = min(max(A.x, B.x), min(A.y, B.y));
    partials[(size_t)ct * M_TOK + row0 + tid] = make_uint2(c1, c2);
  }
}

// ---------------- global best-2 + flag near-ties ----------------
__global__ __launch_bounds__(256) void reduce_kernel(
    const uint2* __restrict__ partials, u32* __restrict__ bestkey,
    int* __restrict__ fidx, int* __restrict__ flaglist, int* __restrict__ cnt) {
  int t = blockIdx.x * 256 + threadIdx.x;
  if (t >= M_TOK) return;
  u32 b1 = 0xFFFFFFFFu, b2 = 0xFFFFFFFFu;
  int bidx = 0;
  for (int ct = 0; ct < 64; ++ct) {
    uint2 e = partials[(size_t)ct * M_TOK + t];
    if (e.x < b1) {
      b2 = min(b1, min(b2, e.y));
      b1 = e.x;
      bidx = ct * 128 + (int)(e.x & 127u);
    } else {
      b2 = min(b2, e.x);
    }
  }
  bestkey[t] = b1;
  fidx[t] = bidx;
  if (qval(b2) - qval(b1) < BAND) flaglist[atomicAdd(cnt, 1)] = t;
}

// ---------------- exact fp32 re-rank for flagged tokens ----------------
__global__ __launch_bounds__(256) void fixup_kernel(
    const float* __restrict__ xs, const float* __restrict__ w,
    const float* __restrict__ wnorm, const uint2* __restrict__ partials,
    const u32* __restrict__ bestkey, const int* __restrict__ flaglist,
    const int* __restrict__ cnt, int* __restrict__ fidx) {
  __shared__ int s_cand[8256];   // 64 blocks x (1 + 128) worst case
  __shared__ int s_n;
  __shared__ u64 s_best;
  const int n_flag = *cnt;
  for (int ii = blockIdx.x; ii < n_flag; ii += gridDim.x) {
    const int t = flaglist[ii];
    if (threadIdx.x == 0) { s_n = 0; s_best = ~0ULL; }
    __syncthreads();
    const float thr = qval(bestkey[t]) + BAND;
    if (threadIdx.x < 64) {
      uint2 e = partials[(size_t)threadIdx.x * M_TOK + t];
      if (qval(e.x) <= thr)
        s_cand[atomicAdd(&s_n, 1)] = (int)threadIdx.x * 128 + (int)(e.x & 127u);
      if (qval(e.y) <= thr) {                // possible hidden 3rd: scan whole block
        int base = atomicAdd(&s_n, 128);
        for (int c = 0; c < 128; ++c) s_cand[base + c] = (int)threadIdx.x * 128 + c;
      }
    }
    __syncthreads();
    const int n = s_n;
    const int wid = threadIdx.x >> 6, lane = threadIdx.x & 63;
    for (int c = wid; c < n; c += 4) {
      const int j = s_cand[c];
      const float4* xr = (const float4*)(xs + (size_t)t * D_K);
      const float4* wr = (const float4*)(w + (size_t)j * D_K);
      float4 a0 = xr[lane * 2], a1 = xr[lane * 2 + 1];
      float4 b0 = wr[lane * 2], b1 = wr[lane * 2 + 1];
      float s = a0.x*b0.x + a0.y*b0.y + a0.z*b0.z + a0.w*b0.w
              + a1.x*b1.x + a1.y*b1.y + a1.z*b1.z + a1.w*b1.w;
      #pragma unroll
      for (int off = 32; off; off >>= 1) s += __shfl_xor(s, off);
      if (lane == 0) {
        float score = wnorm[j] - 2.0f * s;
        u64 k = ((u64)map_f(score) << 32) | (u32)j;
        atomicMin(&s_best, k);
      }
    }
    __syncthreads();
    if (threadIdx.x == 0) fidx[t] = (int)(s_best & 0xFFFFFFFFULL);
    __syncthreads();
  }
}

// ---------------- gather: out = W[idx] (== xs + (W[idx]-xs) within 1 ulp) ----------------
__global__ __launch_bounds__(256) void gather_kernel(const float* __restrict__ w,
                                                     const int* __restrict__ fidx,
                                                     float* __restrict__ out) {
  int e = blockIdx.x * 256 + threadIdx.x;
  int row = e >> 7, off = e & 127;
  ((float4*)out)[e] = ((const float4*)(w + (size_t)fidx[row] * D_K))[off];
}

extern "C" void kernel_launch(void* const* d_in, const int* in_sizes, int n_in,
                              void* d_out, int out_size, void* d_ws, size_t ws_size,
                              hipStream_t stream) {
  const float* xs = (const float*)d_in[0];
  const float* w  = (const float*)d_in[1];
  float* out = (float*)d_out;

  // ws layout (~59 MB; ws proven >= 85 MB in R2)
  char* p = (char*)d_ws;
  f16*   Xh       = (f16*)p;                 p += (size_t)M_TOK * D_K * 2;
  f16*   Wh       = (f16*)p;                 p += (size_t)N_EMB * D_K * 2;
  float* wnorm    = (float*)p;               p += (size_t)N_EMB * 4;
  uint2* partials = (uint2*)p;               p += (size_t)64 * M_TOK * 8;
  u32*   bestkey  = (u32*)p;                 p += (size_t)M_TOK * 4;
  int*   fidx     = (int*)p;                 p += (size_t)M_TOK * 4;
  int*   flaglist = (int*)p;                 p += (size_t)M_TOK * 4;
  int*   cnt      = (int*)p;

  convert_hi_kernel<<<(M_TOK * 128) / 256, 256, 0, stream>>>(xs, Xh, M_TOK * 128);
  convw_norm_kernel<<<N_EMB / 4, 256, 0, stream>>>(w, Wh, wnorm, cnt);
  dist_mfma_kernel<<<(M_TOK / 128) * (N_EMB / 128), 256, 0, stream>>>(Xh, Wh, wnorm, partials);
  reduce_kernel<<<M_TOK / 256, 256, 0, stream>>>(partials, bestkey, fidx, flaglist, cnt);
  fixup_kernel<<<256, 256, 0, stream>>>(xs, w, wnorm, partials, bestkey, flaglist, cnt, fidx);
  gather_kernel<<<(M_TOK * (D_K / 4)) / 256, 256, 0, stream>>>(w, fidx, out);
}

// Round 12
// 493.745 us; speedup vs baseline: 1.0347x; 1.0347x over previous
//
#include <hip/hip_runtime.h>

// VQ codebook nearest-neighbor: xs [32768,512] f32, W [8192,512] f32
// out[i] = W[argmin_j ||xs_i - W_j||^2]
//
// R12: m201-style 8-phase pipelined f16 MFMA pass. 256x256 tile, 8 waves
//      (2M x 4N), BK=64 (8 K-tiles), LDS 128KB = 2dbuf x [A 2x16KB | B 2x16KB].
//      Per iter (2 K-tiles): 8 phases of {ds_read | stage-half -> bar ->
//      lgkm0 -> setprio 16 MFMA -> counted vmcnt -> bar}. vmcnt(2)@ph3,
//      vmcnt(8)@ph7 - loads stay in flight across barriers (T3+T4).
//      + lean u32 best-2 epilogue + exact fp32 fixup (R4/R6/R7-proven).

#define M_TOK 32768
#define N_EMB 8192
#define D_K   512
#define WOFF  2048.0f
#define QMASK 0xFFFFFF00u     // 8 low bits = local col (256-wide); quant 0.0625
#define BAND  0.375f

typedef _Float16 f16;
typedef __attribute__((ext_vector_type(8))) _Float16 f16x8;
typedef __attribute__((ext_vector_type(4))) _Float16 f16x4;
typedef __attribute__((ext_vector_type(4))) float f32x4;
typedef unsigned long long u64;
typedef unsigned int u32;

__device__ __forceinline__ void gload16(const void* g, void* l) {
  __builtin_amdgcn_global_load_lds(
      (const __attribute__((address_space(1))) unsigned int*)g,
      (__attribute__((address_space(3))) unsigned int*)l, 16, 0, 0);
}

__device__ __forceinline__ u32 map_f(float f) {
  u32 u = __float_as_uint(f);
  return u ^ ((u & 0x80000000u) ? 0xFFFFFFFFu : 0x80000000u);
}
__device__ __forceinline__ float qval(u32 key) {
  return __uint_as_float(key & QMASK) - WOFF;
}

// ---------------- fp32 -> f16 X ----------------
__global__ __launch_bounds__(256) void convert_hi_kernel(const float* __restrict__ src,
                                                         f16* __restrict__ dst, int n4) {
  int e = blockIdx.x * 256 + threadIdx.x;
  if (e >= n4) return;
  float4 v = ((const float4*)src)[e];
  f16x4 h; h.x = (f16)v.x; h.y = (f16)v.y; h.z = (f16)v.z; h.w = (f16)v.w;
  *(f16x4*)(dst + (size_t)e * 4) = h;
}

// ---------------- W: convert + ||w||^2 fused ----------------
__global__ __launch_bounds__(256) void convw_norm_kernel(const float* __restrict__ w,
                                                         f16* __restrict__ Wh,
                                                         float* __restrict__ wnorm,
                                                         int* __restrict__ cnt) {
  if (blockIdx.x == 0 && threadIdx.x == 0) *cnt = 0;
  const int row  = blockIdx.x * 4 + (threadIdx.x >> 6);
  const int lane = threadIdx.x & 63;
  const float4* wr = (const float4*)(w + (size_t)row * D_K);
  float4 v0 = wr[lane * 2], v1 = wr[lane * 2 + 1];
  f16x8 h;
  h[0] = (f16)v0.x; h[1] = (f16)v0.y; h[2] = (f16)v0.z; h[3] = (f16)v0.w;
  h[4] = (f16)v1.x; h[5] = (f16)v1.y; h[6] = (f16)v1.z; h[7] = (f16)v1.w;
  *(f16x8*)(Wh + (size_t)row * D_K + lane * 8) = h;
  float s = v0.x*v0.x + v0.y*v0.y + v0.z*v0.z + v0.w*v0.w
          + v1.x*v1.x + v1.y*v1.y + v1.z*v1.z + v1.w*v1.w;
  #pragma unroll
  for (int off = 32; off; off >>= 1) s += __shfl_xor(s, off);
  if (lane == 0) wnorm[row] = s;
}

// ---------------- 8-phase pipelined distance + per-block best-2 ----------------
// Region ledger (buf0 = tiles even, buf1 = odd):
//   tile 2t regions last read: A @ph2(k1), B @ph2 -> overwritten by stages
//   ph3(A2h0) ph4(A2h1) ph5(B2h0) ph6(B2h1), each >=1 junction-barrier after
//   readers' lgkmcnt(0).  tile 2t+1 regions last read ph6 -> overwritten ph7.
// vmcnt: ph3 waits prev-ph7's 8 (tile 2t+1 landed before ph4 reads), leaves
//   own 2; ph7 waits ph3-6's 8 (tile 2t+2 landed before next ph0), leaves 8.
__global__ __launch_bounds__(512, 2) void dist_mfma_kernel(
    const f16* __restrict__ Xh, const f16* __restrict__ Wh,
    const float* __restrict__ wnorm, uint2* __restrict__ partials) {
  __shared__ char smem[131072];   // buf p at p*65536: [A h0|h1 32KB][B h0|h1 32KB]

  int bid = (int)blockIdx.x;
  bid = (bid & 7) * 512 + (bid >> 3);           // XCD swizzle (4096 % 8 == 0)
  const int rt = bid >> 5, ct = bid & 31;
  const int row0 = rt * 256, col0 = ct * 256;

  const int tid  = threadIdx.x;
  const int w    = tid >> 6, lane = tid & 63;
  const int wr   = w >> 2,  wcn  = w & 3;       // 2 M-waves x 4 N-waves
  const int g    = lane >> 4, cl = lane & 15;

  const char* gA = (const char*)Xh + (size_t)row0 * 1024;   // row = 1024 B
  const char* gB = (const char*)Wh + (size_t)col0 * 1024;

  // stage source granule offsets (pre-swizzled: LDS granule (r,g8) holds
  // source granule g8^(r&7) of row r)
  int srcg[2];
  #pragma unroll
  for (int h2 = 0; h2 < 2; ++h2) {
    const int gi = h2 * 512 + tid;
    const int r = gi >> 3, g8 = gi & 7;
    srcg[h2] = r * 1024 + ((g8 ^ (r & 7)) * 16);
  }
  const int dstw = w * 1024;                    // wave-uniform dest base part

  // frag read offsets (within a buffer): row stride 128B, granule (ks*4+g)^(r&7)
  int offA[2][8], offB[2][4];
  #pragma unroll
  for (int ks = 0; ks < 2; ++ks) {
    #pragma unroll
    for (int m = 0; m < 8; ++m) {
      const int r = m * 16 + cl;
      offA[ks][m] = wr * 16384 + r * 128 + (((ks * 4 + g) ^ (r & 7)) * 16);
    }
    #pragma unroll
    for (int n = 0; n < 4; ++n) {
      const int r = (wcn & 1) * 64 + n * 16 + cl;
      offB[ks][n] = 32768 + (wcn >> 1) * 16384 + r * 128 + (((ks * 4 + g) ^ (r & 7)) * 16);
    }
  }

  #define HSTG(op, h, tau)                                                     \
    { const char* gsb = (op) ? gB : gA;                                        \
      _Pragma("unroll") for (int h2 = 0; h2 < 2; ++h2)                         \
        gload16(gsb + (size_t)(h) * 131072 + (tau) * 128 + srcg[h2],           \
                smem + ((tau) & 1) * 65536 + (op) * 32768 + (h) * 16384        \
                     + h2 * 8192 + dstw); }

  f16x8 a[8], b[4];
  #define RD12(bb, ks)                                                         \
    { _Pragma("unroll") for (int m = 0; m < 8; ++m)                            \
        a[m] = *(const f16x8*)(smem + (bb) + offA[ks][m]);                     \
      _Pragma("unroll") for (int n = 0; n < 4; ++n)                            \
        b[n] = *(const f16x8*)(smem + (bb) + offB[ks][n]); }

  f32x4 acc[8][4];
  #pragma unroll
  for (int i = 0; i < 8; i++)
    #pragma unroll
    for (int j = 0; j < 4; j++) acc[i][j] = (f32x4)(0.0f);

  #define QUAD(mb)                                                             \
    { _Pragma("unroll") for (int m = 0; m < 4; ++m)                            \
        _Pragma("unroll") for (int n = 0; n < 4; ++n)                          \
          acc[(mb) + m][n] = __builtin_amdgcn_mfma_f32_16x16x32_f16(           \
              a[(mb) + m], b[n], acc[(mb) + m][n], 0, 0, 0); }

  #define BARX() __builtin_amdgcn_s_barrier()
  #define LG0()  do { asm volatile("s_waitcnt lgkmcnt(0)" ::: "memory");       \
                      __builtin_amdgcn_sched_barrier(0); } while (0)
  #define P1()   __builtin_amdgcn_s_setprio(1)
  #define P0()   __builtin_amdgcn_s_setprio(0)

  // prologue: stage tile0 (buf0), tile1 (buf1); wait tile0, keep tile1 flying
  HSTG(0, 0, 0) HSTG(0, 1, 0) HSTG(1, 0, 0) HSTG(1, 1, 0)
  HSTG(0, 0, 1) HSTG(0, 1, 1) HSTG(1, 0, 1) HSTG(1, 1, 1)
  asm volatile("s_waitcnt vmcnt(8)" ::: "memory");
  BARX();

  #pragma unroll
  for (int t = 0; t < 4; ++t) {
    const int T2 = 2 * t + 2, T3 = 2 * t + 3;
    // ph0: read tile2t k0 -> MFMA lo
    RD12(0, 0);
    BARX(); LG0(); P1(); QUAD(0); P0(); BARX();
    // ph1: MFMA hi
    P1(); QUAD(4); P0(); BARX();
    // ph2: read tile2t k1 -> MFMA lo
    RD12(0, 1);
    BARX(); LG0(); P1(); QUAD(0); P0(); BARX();
    // ph3: stage A(T2)h0; MFMA hi; vmcnt(2) (tile 2t+1 landed for ph4)
    if (t < 3) HSTG(0, 0, T2);
    BARX(); P1(); QUAD(4); P0();
    if (t < 3) { asm volatile("s_waitcnt vmcnt(2)" ::: "memory"); }
    else       { asm volatile("s_waitcnt vmcnt(0)" ::: "memory"); }
    BARX();
    // ph4: read tile2t+1 k0; stage A(T2)h1; MFMA lo
    RD12(65536, 0);
    if (t < 3) HSTG(0, 1, T2);
    BARX(); LG0(); P1(); QUAD(0); P0(); BARX();
    // ph5: stage B(T2)h0; MFMA hi
    if (t < 3) HSTG(1, 0, T2);
    BARX(); P1(); QUAD(4); P0(); BARX();
    // ph6: read tile2t+1 k1; stage B(T2)h1; MFMA lo
    RD12(65536, 1);
    if (t < 3) HSTG(1, 1, T2);
    BARX(); LG0(); P1(); QUAD(0); P0(); BARX();
    // ph7: stage tile T3 (all 4 halves); MFMA hi; vmcnt(8) (tile T2 landed)
    if (t < 3) { HSTG(0, 0, T3) HSTG(0, 1, T3) HSTG(1, 0, T3) HSTG(1, 1, T3) }
    BARX(); P1(); QUAD(4); P0();
    asm volatile("s_waitcnt vmcnt(8)" ::: "memory");
    BARX();
  }
  #undef QUAD
  #undef RD12
  #undef HSTG

  __syncthreads();   // full drain before LDS reuse

  // ---- epilogue: u32 keys (quantized bits | 8-bit local col), best-2 ----
  float wnp[4];
  u32 colb[4];
  #pragma unroll
  for (int n = 0; n < 4; ++n) {
    wnp[n]  = wnorm[col0 + wcn * 64 + n * 16 + cl] + WOFF;
    colb[n] = (u32)(wcn * 64 + n * 16 + cl);
  }

  uint2* cmb = (uint2*)smem;   // [256 rows][4 wcn] = 8KB

  #pragma unroll
  for (int m = 0; m < 8; ++m) {
    #pragma unroll
    for (int r = 0; r < 4; ++r) {
      float s0 = fmaf(-2.0f, acc[m][0][r], wnp[0]);
      float s1 = fmaf(-2.0f, acc[m][1][r], wnp[1]);
      float s2 = fmaf(-2.0f, acc[m][2][r], wnp[2]);
      float s3 = fmaf(-2.0f, acc[m][3][r], wnp[3]);
      u32 k0 = (__float_as_uint(s0) & QMASK) | colb[0];
      u32 k1 = (__float_as_uint(s1) & QMASK) | colb[1];
      u32 k2 = (__float_as_uint(s2) & QMASK) | colb[2];
      u32 k3 = (__float_as_uint(s3) & QMASK) | colb[3];
      u32 pa = min(k0, k1), pb = max(k0, k1);
      u32 pc = min(k2, k3), pd = max(k2, k3);
      u32 c1 = min(pa, pc);
      u32 c2 = min(max(pa, pc), min(pb, pd));
      #pragma unroll
      for (int off = 1; off < 16; off <<= 1) {
        u32 o1 = __shfl_xor(c1, off), o2 = __shfl_xor(c2, off);
        u32 n1 = min(c1, o1);
        c2 = min(min(c2, o2), max(c1, o1));
        c1 = n1;
      }
      if (cl == 0) cmb[(wr * 128 + m * 16 + g * 4 + r) * 4 + wcn] = make_uint2(c1, c2);
    }
  }
  __syncthreads();
  if (tid < 256) {
    u32 b1 = 0xFFFFFFFFu, b2 = 0xFFFFFFFFu;
    #pragma unroll
    for (int q = 0; q < 4; ++q) {
      uint2 e = cmb[tid * 4 + q];
      u32 m1 = min(b1, e.x);
      b2 = min(max(b1, e.x), min(b2, e.y));
      b1 = m1;
    }
    partials[(size_t)ct * M_TOK + row0 + tid] = make_uint2(b1, b2);
  }
}

// ---------------- global best-2 + flag near-ties ----------------
__global__ __launch_bounds__(256) void reduce_kernel(
    const uint2* __restrict__ partials, u32* __restrict__ bestkey,
    int* __restrict__ fidx, int* __restrict__ flaglist, int* __restrict__ cnt) {
  int t = blockIdx.x * 256 + threadIdx.x;
  if (t >= M_TOK) return;
  u32 b1 = 0xFFFFFFFFu, b2 = 0xFFFFFFFFu;
  int bidx = 0;
  for (int ct = 0; ct < 32; ++ct) {
    uint2 e = partials[(size_t)ct * M_TOK + t];
    if (e.x < b1) {
      b2 = min(b1, min(b2, e.y));
      b1 = e.x;
      bidx = ct * 256 + (int)(e.x & 255u);
    } else {
      b2 = min(b2, e.x);
    }
  }
  bestkey[t] = b1;
  fidx[t] = bidx;
  if (qval(b2) - qval(b1) < BAND) flaglist[atomicAdd(cnt, 1)] = t;
}

// ---------------- exact fp32 re-rank for flagged tokens ----------------
__global__ __launch_bounds__(256) void fixup_kernel(
    const float* __restrict__ xs, const float* __restrict__ w,
    const float* __restrict__ wnorm, const uint2* __restrict__ partials,
    const u32* __restrict__ bestkey, const int* __restrict__ flaglist,
    const int* __restrict__ cnt, int* __restrict__ fidx) {
  __shared__ int s_cand[8256];
  __shared__ int s_n;
  __shared__ u64 s_best;
  const int n_flag = *cnt;
  for (int ii = blockIdx.x; ii < n_flag; ii += gridDim.x) {
    const int t = flaglist[ii];
    if (threadIdx.x == 0) { s_n = 0; s_best = ~0ULL; }
    __syncthreads();
    const float thr = qval(bestkey[t]) + BAND;
    if (threadIdx.x < 32) {
      uint2 e = partials[(size_t)threadIdx.x * M_TOK + t];
      if (qval(e.x) <= thr)
        s_cand[atomicAdd(&s_n, 1)] = (int)threadIdx.x * 256 + (int)(e.x & 255u);
      if (qval(e.y) <= thr) {                // possible hidden 3rd: scan whole block
        int base = atomicAdd(&s_n, 256);
        for (int c = 0; c < 256; ++c) s_cand[base + c] = (int)threadIdx.x * 256 + c;
      }
    }
    __syncthreads();
    const int n = s_n;
    const int wid = threadIdx.x >> 6, lane = threadIdx.x & 63;
    for (int c = wid; c < n; c += 4) {
      const int j = s_cand[c];
      const float4* xr = (const float4*)(xs + (size_t)t * D_K);
      const float4* wr = (const float4*)(w + (size_t)j * D_K);
      float4 a0 = xr[lane * 2], a1 = xr[lane * 2 + 1];
      float4 b0 = wr[lane * 2], b1 = wr[lane * 2 + 1];
      float s = a0.x*b0.x + a0.y*b0.y + a0.z*b0.z + a0.w*b0.w
              + a1.x*b1.x + a1.y*b1.y + a1.z*b1.z + a1.w*b1.w;
      #pragma unroll
      for (int off = 32; off; off >>= 1) s += __shfl_xor(s, off);
      if (lane == 0) {
        float score = wnorm[j] - 2.0f * s;
        u64 k = ((u64)map_f(score) << 32) | (u32)j;
        atomicMin(&s_best, k);
      }
    }
    __syncthreads();
    if (threadIdx.x == 0) fidx[t] = (int)(s_best & 0xFFFFFFFFULL);
    __syncthreads();
  }
}

// ---------------- gather: out = xs + (W[idx] - xs)  (mimic ref arithmetic) ----------------
__global__ __launch_bounds__(256) void gather_kernel(const float* __restrict__ xs,
                                                     const float* __restrict__ w,
                                                     const int* __restrict__ fidx,
                                                     float* __restrict__ out) {
  int e = blockIdx.x * 256 + threadIdx.x;
  int row = e >> 7, off = e & 127;
  float4 xv = ((const float4*)(xs + (size_t)row * D_K))[off];
  float4 wv = ((const float4*)(w  + (size_t)fidx[row] * D_K))[off];
  float4 o;
  o.x = xv.x + (wv.x - xv.x);
  o.y = xv.y + (wv.y - xv.y);
  o.z = xv.z + (wv.z - xv.z);
  o.w = xv.w + (wv.w - xv.w);
  ((float4*)out)[e] = o;
}

extern "C" void kernel_launch(void* const* d_in, const int* in_sizes, int n_in,
                              void* d_out, int out_size, void* d_ws, size_t ws_size,
                              hipStream_t stream) {
  const float* xs = (const float*)d_in[0];
  const float* w  = (const float*)d_in[1];
  float* out = (float*)d_out;

  // ws layout (~51 MB; ws proven >= 85 MB in R2)
  char* p = (char*)d_ws;
  f16*   Xh       = (f16*)p;                 p += (size_t)M_TOK * D_K * 2;
  f16*   Wh       = (f16*)p;                 p += (size_t)N_EMB * D_K * 2;
  float* wnorm    = (float*)p;               p += (size_t)N_EMB * 4;
  uint2* partials = (uint2*)p;               p += (size_t)32 * M_TOK * 8;
  u32*   bestkey  = (u32*)p;                 p += (size_t)M_TOK * 4;
  int*   fidx     = (int*)p;                 p += (size_t)M_TOK * 4;
  int*   flaglist = (int*)p;                 p += (size_t)M_TOK * 4;
  int*   cnt      = (int*)p;

  convert_hi_kernel<<<(M_TOK * 128) / 256, 256, 0, stream>>>(xs, Xh, M_TOK * 128);
  convw_norm_kernel<<<N_EMB / 4, 256, 0, stream>>>(w, Wh, wnorm, cnt);
  dist_mfma_kernel<<<(M_TOK / 256) * (N_EMB / 256), 512, 0, stream>>>(Xh, Wh, wnorm, partials);
  reduce_kernel<<<M_TOK / 256, 256, 0, stream>>>(partials, bestkey, fidx, flaglist, cnt);
  fixup_kernel<<<256, 256, 0, stream>>>(xs, w, wnorm, partials, bestkey, flaglist, cnt, fidx);
  gather_kernel<<<(M_TOK * (D_K / 4)) / 256, 256, 0, stream>>>(xs, w, fidx, out);
}

// Round 13
// 445.303 us; speedup vs baseline: 1.1473x; 1.1088x over previous
//
#include <hip/hip_runtime.h>

// VQ codebook nearest-neighbor: xs [32768,512] f32, W [8192,512] f32
// out[i] = W[argmin_j ||xs_i - W_j||^2]
//
// R13: INT8 coarse pass (mfma_i32_16x16x64_i8 = 2x f16 rate, half the bytes
//      through HBM/LDS) on the R11-proven 128x128 / 4-wave / dbuf structure
//      (byte-identical fragment layout to the f16 path). Distance error
//      sigma ~0.82 -> BAND 5.5 (4.8 sigma of pair error). Exact fp32 fixup
//      for the ~30% flagged near-tie tokens (logic proven R4-R12).

#define M_TOK 32768
#define N_EMB 8192
#define D_K   512
#define WOFF  2048.0f
#define QMASK 0xFFFFFF80u     // 7 low bits = local col (128-wide tile)
#define BAND  5.5f
#define NT    8               // K-tiles of 64 (i8)
#define SCALE 22.6786f        // 127/5.6
#define M2C   (-2.0f / (SCALE * SCALE))

typedef __attribute__((ext_vector_type(4))) int   i32x4;
typedef __attribute__((ext_vector_type(4))) float f32x4;
typedef unsigned long long u64;
typedef unsigned int u32;

__device__ __forceinline__ void gload16(const void* g, void* l) {
  __builtin_amdgcn_global_load_lds(
      (const __attribute__((address_space(1))) unsigned int*)g,
      (__attribute__((address_space(3))) unsigned int*)l, 16, 0, 0);
}

__device__ __forceinline__ u32 map_f(float f) {   // exact order-preserving (fixup)
  u32 u = __float_as_uint(f);
  return u ^ ((u & 0x80000000u) ? 0xFFFFFFFFu : 0x80000000u);
}
__device__ __forceinline__ float qval(u32 key) {  // quantized approx value
  return __uint_as_float(key & QMASK) - WOFF;
}

__device__ __forceinline__ int q8(float x) {
  int v = __float2int_rn(x * SCALE);
  return v < -127 ? -127 : (v > 127 ? 127 : v);
}

// ---------------- X: f32 -> i8 (16 elems / thread) ----------------
__global__ __launch_bounds__(256) void quant_x_kernel(const float* __restrict__ src,
                                                      char* __restrict__ dst, int n16) {
  int e = blockIdx.x * 256 + threadIdx.x;
  if (e >= n16) return;
  const float4* s4 = (const float4*)src + (size_t)e * 4;
  char out[16];
  #pragma unroll
  for (int i = 0; i < 4; ++i) {
    float4 v = s4[i];
    out[i * 4 + 0] = (char)q8(v.x);
    out[i * 4 + 1] = (char)q8(v.y);
    out[i * 4 + 2] = (char)q8(v.z);
    out[i * 4 + 3] = (char)q8(v.w);
  }
  ((int4*)dst)[e] = *(const int4*)out;
}

// ---------------- W: quantize + exact ||w||^2 fused ----------------
__global__ __launch_bounds__(256) void quant_w_kernel(const float* __restrict__ w,
                                                      char* __restrict__ Wq,
                                                      float* __restrict__ wnorm,
                                                      int* __restrict__ cnt) {
  if (blockIdx.x == 0 && threadIdx.x == 0) *cnt = 0;
  const int row  = blockIdx.x * 4 + (threadIdx.x >> 6);
  const int lane = threadIdx.x & 63;
  const float4* wr = (const float4*)(w + (size_t)row * D_K);
  float4 v0 = wr[lane * 2], v1 = wr[lane * 2 + 1];
  char out[8];
  out[0] = (char)q8(v0.x); out[1] = (char)q8(v0.y);
  out[2] = (char)q8(v0.z); out[3] = (char)q8(v0.w);
  out[4] = (char)q8(v1.x); out[5] = (char)q8(v1.y);
  out[6] = (char)q8(v1.z); out[7] = (char)q8(v1.w);
  *(int2*)(Wq + (size_t)row * D_K + lane * 8) = *(const int2*)out;
  float s = v0.x*v0.x + v0.y*v0.y + v0.z*v0.z + v0.w*v0.w
          + v1.x*v1.x + v1.y*v1.y + v1.z*v1.z + v1.w*v1.w;
  #pragma unroll
  for (int off = 32; off; off >>= 1) s += __shfl_xor(s, off);
  if (lane == 0) wnorm[row] = s;
}

// ---------------- i8 approx distance + per-block best-2 ----------------
// 128x128 tile, 4 waves (2x2), wave-tile 64x64, BK=64 (i8), dbuf 2x16KB.
// Byte layout identical to the R11 f16 kernel (rows 64B, 16B granules,
// (r>>1)&3 XOR swizzle - measured ~0 conflicts). Dbuf safety: R10-proven
// (stage(t+1) -> buf^1 after prior __syncthreads drained its readers).
__global__ __launch_bounds__(256, 3) void dist_mfma_kernel(
    const char* __restrict__ Xq, const char* __restrict__ Wq,
    const float* __restrict__ wnorm, uint2* __restrict__ partials) {
  __shared__ char smem[32768];   // buf b at b*16384: [A 8KB | B 8KB]

  int bid = (int)blockIdx.x;
  const int swz = (bid & 7) * 2048 + (bid >> 3);   // XCD swizzle (16384 % 8 == 0)
  const int rt = swz & 255, ct = swz >> 8;          // rt fast -> B-panel L2-hot
  const int row0 = rt * 128, col0 = ct * 128;

  const int tid  = threadIdx.x;
  const int w    = tid >> 6, lane = tid & 63;
  const int wr   = w >> 1,  wc   = w & 1;           // 2x2 wave grid
  const int g    = lane >> 4, cl = lane & 15;

  const char* gA = Xq + (size_t)row0 * D_K;         // row = 512 B
  const char* gB = Wq + (size_t)col0 * D_K;

  // stage source offsets (pre-swizzled): chunk c = q*256+tid (16B), row r=c>>2
  int srcoff[2];
  #pragma unroll
  for (int q = 0; q < 2; ++q) {
    const int c = q * 256 + tid;
    const int r = c >> 2;
    srcoff[q] = r * 512 + (((c & 3) ^ ((r >> 1) & 3)) * 16);
  }

  // LDS frag-read offsets (row stride 64B, slot g ^ ((row>>1)&3))
  int offA[4], offB[4];
  #pragma unroll
  for (int m = 0; m < 4; ++m) {
    const int rl = wr * 64 + m * 16 + cl;
    offA[m] = rl * 64 + ((g ^ ((rl >> 1) & 3)) * 16);
  }
  #pragma unroll
  for (int n = 0; n < 4; ++n) {
    const int rl = wc * 64 + n * 16 + cl;
    offB[n] = 8192 + rl * 64 + ((g ^ ((rl >> 1) & 3)) * 16);
  }

  #define STG(bo, kt)                                                          \
    { _Pragma("unroll") for (int q = 0; q < 2; ++q)                            \
        gload16(gA + srcoff[q] + (kt) * 64,                                    \
                smem + (bo) + q * 4096 + w * 1024);                            \
      _Pragma("unroll") for (int q = 0; q < 2; ++q)                            \
        gload16(gB + srcoff[q] + (kt) * 64,                                    \
                smem + (bo) + 8192 + q * 4096 + w * 1024); }

  i32x4 acc[4][4];
  #pragma unroll
  for (int i = 0; i < 4; i++)
    #pragma unroll
    for (int j = 0; j < 4; j++) acc[i][j] = (i32x4)(0);

  STG(0, 0);
  __syncthreads();

  for (int t = 0; t < NT; ++t) {
    const int rb = (t & 1) * 16384, sb = rb ^ 16384;
    if (t < NT - 1) STG(sb, t + 1);

    i32x4 a[4], b[4];
    #pragma unroll
    for (int m = 0; m < 4; ++m) a[m] = *(const i32x4*)(smem + rb + offA[m]);
    #pragma unroll
    for (int n = 0; n < 4; ++n) b[n] = *(const i32x4*)(smem + rb + offB[n]);

    #pragma unroll
    for (int m = 0; m < 4; ++m)
      #pragma unroll
      for (int n = 0; n < 4; ++n)
        acc[m][n] = __builtin_amdgcn_mfma_i32_16x16x64_i8(a[m], b[n], acc[m][n], 0, 0, 0);

    __syncthreads();   // drains vmcnt (stage landed) + lgkm (buf reads done)
  }
  #undef STG

  // ---- epilogue: u32 keys (quantized bits | 7-bit local col), best-2 ----
  float wnp[4];
  u32 colb[4];
  #pragma unroll
  for (int n = 0; n < 4; ++n) {
    const int colL = wc * 64 + n * 16 + cl;
    wnp[n]  = wnorm[col0 + colL] + WOFF;   // score = wnorm + WOFF - 2*dot/S^2
    colb[n] = (u32)colL;
  }

  uint2* cmb = (uint2*)smem;   // [128 rows][2 wc] = 2KB (loop fully drained)

  #pragma unroll
  for (int m = 0; m < 4; ++m) {
    #pragma unroll
    for (int r = 0; r < 4; ++r) {
      float s0 = fmaf((float)acc[m][0][r], M2C, wnp[0]);
      float s1 = fmaf((float)acc[m][1][r], M2C, wnp[1]);
      float s2 = fmaf((float)acc[m][2][r], M2C, wnp[2]);
      float s3 = fmaf((float)acc[m][3][r], M2C, wnp[3]);
      u32 k0 = (__float_as_uint(s0) & QMASK) | colb[0];
      u32 k1 = (__float_as_uint(s1) & QMASK) | colb[1];
      u32 k2 = (__float_as_uint(s2) & QMASK) | colb[2];
      u32 k3 = (__float_as_uint(s3) & QMASK) | colb[3];
      u32 pa = min(k0, k1), pb = max(k0, k1);
      u32 pc = min(k2, k3), pd = max(k2, k3);
      u32 c1 = min(pa, pc);
      u32 c2 = min(max(pa, pc), min(pb, pd));
      #pragma unroll
      for (int off = 1; off < 16; off <<= 1) {
        u32 o1 = __shfl_xor(c1, off), o2 = __shfl_xor(c2, off);
        u32 n1 = min(c1, o1);
        c2 = min(min(c2, o2), max(c1, o1));
        c1 = n1;
      }
      if (cl == 0) cmb[(wr * 64 + m * 16 + g * 4 + r) * 2 + wc] = make_uint2(c1, c2);
    }
  }
  __syncthreads();
  if (tid < 128) {
    uint2 A = cmb[tid * 2], B = cmb[tid * 2 + 1];
    u32 c1 = min(A.x, B.x);
    u32 c2 = min(max(A.x, B.x), min(A.y, B.y));
    partials[(size_t)ct * M_TOK + row0 + tid] = make_uint2(c1, c2);
  }
}

// ---------------- global best-2 + flag near-ties ----------------
__global__ __launch_bounds__(256) void reduce_kernel(
    const uint2* __restrict__ partials, u32* __restrict__ bestkey,
    int* __restrict__ fidx, int* __restrict__ flaglist, int* __restrict__ cnt) {
  int t = blockIdx.x * 256 + threadIdx.x;
  if (t >= M_TOK) return;
  u32 b1 = 0xFFFFFFFFu, b2 = 0xFFFFFFFFu;
  int bidx = 0;
  for (int ct = 0; ct < 64; ++ct) {
    uint2 e = partials[(size_t)ct * M_TOK + t];
    if (e.x < b1) {
      b2 = min(b1, min(b2, e.y));
      b1 = e.x;
      bidx = ct * 128 + (int)(e.x & 127u);
    } else {
      b2 = min(b2, e.x);
    }
  }
  bestkey[t] = b1;
  fidx[t] = bidx;
  if (qval(b2) - qval(b1) < BAND) flaglist[atomicAdd(cnt, 1)] = t;
}

// ---------------- exact fp32 re-rank for flagged tokens ----------------
__global__ __launch_bounds__(256) void fixup_kernel(
    const float* __restrict__ xs, const float* __restrict__ w,
    const float* __restrict__ wnorm, const uint2* __restrict__ partials,
    const u32* __restrict__ bestkey, const int* __restrict__ flaglist,
    const int* __restrict__ cnt, int* __restrict__ fidx) {
  __shared__ int s_cand[8256];   // 64 blocks x (1 + 128) worst case
  __shared__ int s_n;
  __shared__ u64 s_best;
  const int n_flag = *cnt;
  for (int ii = blockIdx.x; ii < n_flag; ii += gridDim.x) {
    const int t = flaglist[ii];
    if (threadIdx.x == 0) { s_n = 0; s_best = ~0ULL; }
    __syncthreads();
    const float thr = qval(bestkey[t]) + BAND;
    if (threadIdx.x < 64) {
      uint2 e = partials[(size_t)threadIdx.x * M_TOK + t];
      if (qval(e.x) <= thr)
        s_cand[atomicAdd(&s_n, 1)] = (int)threadIdx.x * 128 + (int)(e.x & 127u);
      if (qval(e.y) <= thr) {                // possible hidden 3rd: scan whole block
        int base = atomicAdd(&s_n, 128);
        for (int c = 0; c < 128; ++c) s_cand[base + c] = (int)threadIdx.x * 128 + c;
      }
    }
    __syncthreads();
    const int n = s_n;
    const int wid = threadIdx.x >> 6, lane = threadIdx.x & 63;
    for (int c = wid; c < n; c += 4) {
      const int j = s_cand[c];
      const float4* xr = (const float4*)(xs + (size_t)t * D_K);
      const float4* wr = (const float4*)(w + (size_t)j * D_K);
      float4 a0 = xr[lane * 2], a1 = xr[lane * 2 + 1];
      float4 b0 = wr[lane * 2], b1 = wr[lane * 2 + 1];
      float s = a0.x*b0.x + a0.y*b0.y + a0.z*b0.z + a0.w*b0.w
              + a1.x*b1.x + a1.y*b1.y + a1.z*b1.z + a1.w*b1.w;
      #pragma unroll
      for (int off = 32; off; off >>= 1) s += __shfl_xor(s, off);
      if (lane == 0) {
        float score = wnorm[j] - 2.0f * s;
        u64 k = ((u64)map_f(score) << 32) | (u32)j;
        atomicMin(&s_best, k);
      }
    }
    __syncthreads();
    if (threadIdx.x == 0) fidx[t] = (int)(s_best & 0xFFFFFFFFULL);
    __syncthreads();
  }
}

// ---------------- gather: out = xs + (W[idx] - xs)  (mimic ref arithmetic) ----------------
__global__ __launch_bounds__(256) void gather_kernel(const float* __restrict__ xs,
                                                     const float* __restrict__ w,
                                                     const int* __restrict__ fidx,
                                                     float* __restrict__ out) {
  int e = blockIdx.x * 256 + threadIdx.x;
  int row = e >> 7, off = e & 127;
  float4 xv = ((const float4*)(xs + (size_t)row * D_K))[off];
  float4 wv = ((const float4*)(w  + (size_t)fidx[row] * D_K))[off];
  float4 o;
  o.x = xv.x + (wv.x - xv.x);
  o.y = xv.y + (wv.y - xv.y);
  o.z = xv.z + (wv.z - xv.z);
  o.w = xv.w + (wv.w - xv.w);
  ((float4*)out)[e] = o;
}

extern "C" void kernel_launch(void* const* d_in, const int* in_sizes, int n_in,
                              void* d_out, int out_size, void* d_ws, size_t ws_size,
                              hipStream_t stream) {
  const float* xs = (const float*)d_in[0];
  const float* w  = (const float*)d_in[1];
  float* out = (float*)d_out;

  // ws layout (~38 MB; ws proven >= 85 MB in R2)
  char* p = (char*)d_ws;
  char*  Xq       = p;                       p += (size_t)M_TOK * D_K;        // 16 MB
  char*  Wq       = p;                       p += (size_t)N_EMB * D_K;        //  4 MB
  float* wnorm    = (float*)p;               p += (size_t)N_EMB * 4;
  uint2* partials = (uint2*)p;               p += (size_t)64 * M_TOK * 8;     // 16 MB
  u32*   bestkey  = (u32*)p;                 p += (size_t)M_TOK * 4;
  int*   fidx     = (int*)p;                 p += (size_t)M_TOK * 4;
  int*   flaglist = (int*)p;                 p += (size_t)M_TOK * 4;
  int*   cnt      = (int*)p;

  quant_x_kernel<<<(M_TOK * D_K / 16) / 256, 256, 0, stream>>>(xs, Xq, M_TOK * D_K / 16);
  quant_w_kernel<<<N_EMB / 4, 256, 0, stream>>>(w, Wq, wnorm, cnt);
  dist_mfma_kernel<<<(M_TOK / 128) * (N_EMB / 128), 256, 0, stream>>>(Xq, Wq, wnorm, partials);
  reduce_kernel<<<M_TOK / 256, 256, 0, stream>>>(partials, bestkey, fidx, flaglist, cnt);
  fixup_kernel<<<512, 256, 0, stream>>>(xs, w, wnorm, partials, bestkey, flaglist, cnt, fidx);
  gather_kernel<<<(M_TOK * (D_K / 4)) / 256, 256, 0, stream>>>(xs, w, fidx, out);
}